// Round 2
// baseline (216.086 us; speedup 1.0000x reference)
//
#include <hip/hip_runtime.h>
#include <math.h>

#define C_ 512
#define D_ 256
#define KS_ 4
#define TOPK_ 10
#define NEG 1e20f

// chunk permutation: XOR bit0 with bit3 (involution). Mixes chunk parity so a
// wave's 64 ds_read_b128 addresses (chunks 2l / 2l+1) cover all 8 bank groups.
__device__ __forceinline__ int csw2(int g) { return g ^ ((g >> 3) & 1); }

#define BSTR 516   // b_s row stride in floats: ==4 (mod 32) -> transposed writes conflict-free; *4B ==0 mod 16 -> b128 aligned
#define ASTR 20    // a_s row stride: *4B = 80 ==0 mod 16

extern "C" __global__ __launch_bounds__(256, 4)
void graph_learner(const float* __restrict__ ctx,
                   const int* __restrict__ cmask,
                   const float* __restrict__ W,
                   const float* __restrict__ mu_g,
                   const float* __restrict__ pr_g,
                   float* __restrict__ out)
{
    __shared__ __align__(16) float wbar_s[D_];
    __shared__ __align__(16) float a_s[16 * ASTR];   // A k-slice, transposed: a_s[kk*ASTR + r], r=0..15
    __shared__ __align__(16) float b_s[16 * BSTR];   // B k-slice, transposed+swizzled: b_s[kk*BSTR + 4*csw2(e>>2) + (e&3)]
    __shared__ unsigned int vmask_s[16];

    const int tid  = threadIdx.x;
    const int lane = tid & 63;
    const int wv   = tid >> 6;
    const int w4   = wv * 4;

    // XCD swizzle: blocks sharing one ctx[b,t] panel (512 KB) land on one XCD's L2
    const int blk = blockIdx.x;
    const int bt  = (blk & 7) * 4 + ((blk >> 3) & 3);   // 0..31
    const int c0  = (blk >> 5) * 16;                    // row tile 0..496
    const int b   = bt >> 3;

    const float* ctx_bt = ctx + (size_t)bt * (C_ * D_);
    const int*   mask_b = cmask + b * C_;

    // wbar = mean_p relu(W[p,:])
    {
        float w0 = W[tid], w1 = W[D_ + tid], w2 = W[2 * D_ + tid], w3 = W[3 * D_ + tid];
        wbar_s[tid] = 0.25f * (fmaxf(w0, 0.f) + fmaxf(w1, 0.f) + fmaxf(w2, 0.f) + fmaxf(w3, 0.f));
    }
    if (tid < 16) {
        unsigned int m = 0;
        for (int i = 0; i < 32; ++i)
            m |= (mask_b[tid * 32 + i] > 0 ? 1u : 0u) << i;
        vmask_s[tid] = m;
    }
    // zero this block's own output region (4 ks x 16 rows x 512); barriers below
    // order these stores before the epilogue scatter to the same region.
    {
        const float4 z = make_float4(0.f, 0.f, 0.f, 0.f);
        #pragma unroll
        for (int ks = 0; ks < KS_; ++ks) {
            float* ob = out + ((size_t)(bt * KS_ + ks) * C_ + c0) * C_;
            #pragma unroll
            for (int i = 0; i < 8; ++i)
                *(float4*)(ob + (size_t)(tid + i * 256) * 4) = z;
        }
    }

    // ---- hoisted staging geometry (constant across k-tiles) ----
    // B: thread loads float4 = ctx[r_i][kt*16 + 4*bq ..], r_i = brow + i*64
    const int brow = tid >> 2;
    const int bq   = tid & 3;
    const float* bsrc = ctx_bt + (size_t)brow * D_ + bq * 4;
    // LDS dst: row (4*bq + j), col 4*csw2(r>>2) + (r&3); csw2(g0+16i) = csw2(g0)+16i
    const int bwbase = (4 * bq) * BSTR + 4 * csw2(brow >> 2) + (brow & 3);
    // A: threads 0..63 load float4 = ctx[c0 + ar][kt*16 + 4*aq ..]
    const int ar_ = tid >> 2;        // 0..15 (valid when tid<64)
    const int aq  = tid & 3;
    const float* asrc = ctx_bt + (size_t)(c0 + ar_) * D_ + aq * 4;
    const int awbase = (4 * aq) * ASTR + ar_;
    // FMA-loop read addresses (chunk-swizzled)
    const int bc0 = 4 * csw2(2 * lane);
    const int bc1 = 4 * csw2(2 * lane + 1);

    float4 bregs[8];
    float4 areg;
    {   // prologue load, k-tile 0
        #pragma unroll
        for (int i = 0; i < 8; ++i)
            bregs[i] = *(const float4*)(bsrc + (size_t)i * 64 * D_);
        if (tid < 64) areg = *(const float4*)(asrc);
    }

    float acc[4][8];
    #pragma unroll
    for (int j = 0; j < 4; ++j)
        #pragma unroll
        for (int i = 0; i < 8; ++i) acc[j][i] = 0.f;

    for (int kt = 0; kt < 16; ++kt) {
        __syncthreads();                 // previous slice fully consumed (and wbar ready at kt=0)
        // write staged registers -> LDS (transposed, conflict-free)
        #pragma unroll
        for (int i = 0; i < 8; ++i) {
            b_s[bwbase + 0 * BSTR + i * 64] = bregs[i].x;
            b_s[bwbase + 1 * BSTR + i * 64] = bregs[i].y;
            b_s[bwbase + 2 * BSTR + i * 64] = bregs[i].z;
            b_s[bwbase + 3 * BSTR + i * 64] = bregs[i].w;
        }
        if (tid < 64) {
            float4 wb = *(const float4*)(wbar_s + kt * 16 + aq * 4);
            a_s[awbase + 0 * ASTR] = areg.x * wb.x;
            a_s[awbase + 1 * ASTR] = areg.y * wb.y;
            a_s[awbase + 2 * ASTR] = areg.z * wb.z;
            a_s[awbase + 3 * ASTR] = areg.w * wb.w;
        }
        __syncthreads();
        if (kt < 15) {                   // T14: issue next-slice loads, latency hides under FMA
            #pragma unroll
            for (int i = 0; i < 8; ++i)
                bregs[i] = *(const float4*)(bsrc + (size_t)i * 64 * D_ + (kt + 1) * 16);
            if (tid < 64) areg = *(const float4*)(asrc + (kt + 1) * 16);
        }
        #pragma unroll
        for (int kk = 0; kk < 16; ++kk) {
            float4 av  = *(const float4*)(a_s + kk * ASTR + w4);       // wave-uniform broadcast
            float4 bv0 = *(const float4*)(b_s + kk * BSTR + bc0);
            float4 bv1 = *(const float4*)(b_s + kk * BSTR + bc1);
            float ar4[4] = {av.x, av.y, av.z, av.w};
            float br[8]  = {bv0.x, bv0.y, bv0.z, bv0.w, bv1.x, bv1.y, bv1.z, bv1.w};
            #pragma unroll
            for (int j = 0; j < 4; ++j)
                #pragma unroll
                for (int i = 0; i < 8; ++i)
                    acc[j][i] += ar4[j] * br[i];   // sequential over d: bit-identical to ref
        }
    }

    // ---- epilogue: mask, top-10, softmax, spatial, scatter (numerics unchanged) ----
    const unsigned int em8 = (vmask_s[lane >> 2] >> ((lane & 3) * 8)) & 0xffu;
    const float mu0 = mu_g[0], mu1 = mu_g[1], mu2 = mu_g[2], mu3 = mu_g[3];
    const float pr0 = pr_g[0], pr1 = pr_g[1], pr2 = pr_g[2], pr3 = pr_g[3];

    #pragma unroll
    for (int jr = 0; jr < 4; ++jr) {
        const int c  = c0 + w4 + jr;
        const int vr = mask_b[c];
        float row[8];
        #pragma unroll
        for (int i = 0; i < 8; ++i) {
            bool ok = (vr > 0) && ((em8 >> i) & 1u);
            row[i] = ok ? acc[jr][i] : -NEG;
        }
        float tv[TOPK_];
        int   te[TOPK_];
        unsigned int taken = 0;
        #pragma unroll
        for (int j = 0; j < TOPK_; ++j) {
            float lv = -3.3e38f;
            int   li = 0;
            #pragma unroll
            for (int i = 0; i < 8; ++i) {
                bool better = (!((taken >> i) & 1u)) && (row[i] > lv);
                lv = better ? row[i] : lv;
                li = better ? i : li;
            }
            int le = lane * 8 + li;
            #pragma unroll
            for (int off = 1; off < 64; off <<= 1) {
                float ov = __shfl_xor(lv, off);
                int   oe = __shfl_xor(le, off);
                bool take = (ov > lv) || (ov == lv && oe < le);
                lv = take ? ov : lv;
                le = take ? oe : le;
            }
            tv[j] = lv;
            te[j] = le;
            if ((le >> 3) == lane) taken |= 1u << (le & 7);
        }
        const float mx = tv[0];
        float ssum = 0.f;
        #pragma unroll
        for (int j = 0; j < TOPK_; ++j) ssum += expf(tv[j] - mx);

        if (lane < 40) {
            const int ksq = lane / 10;
            const int myj = lane - ksq * 10;
            const float mu = (ksq == 0) ? mu0 : (ksq == 1) ? mu1 : (ksq == 2) ? mu2 : mu3;
            const float pr = (ksq == 0) ? pr0 : (ksq == 1) ? pr1 : (ksq == 2) ? pr2 : pr3;
            float sps = 0.f, spj = 0.f, tvj = 0.f;
            int ej = 0;
            #pragma unroll
            for (int j = 0; j < TOPK_; ++j) {
                float d = fabsf((float)(te[j] - c));
                d = fminf(d, 160.f) * (1.0f / 160.0f);
                float x  = d - mu;
                float sp = expf(-0.5f * x * x * pr * pr);
                sps += sp;
                if (j == myj) { spj = sp; tvj = tv[j]; ej = te[j]; }
            }
            float val = (expf(tvj - mx) / ssum) * (spj / sps);
            out[((size_t)(bt * KS_ + ksq) * C_ + c) * C_ + ej] = val;
        }
    }
}

extern "C" void kernel_launch(void* const* d_in, const int* in_sizes, int n_in,
                              void* d_out, int out_size, void* d_ws, size_t ws_size,
                              hipStream_t stream) {
    (void)in_sizes; (void)n_in; (void)d_ws; (void)ws_size; (void)out_size;
    const float* ctx   = (const float*)d_in[0];
    const int*   cmask = (const int*)d_in[1];
    const float* W     = (const float*)d_in[2];
    const float* mu    = (const float*)d_in[3];
    const float* pr    = (const float*)d_in[4];
    graph_learner<<<dim3(1024), dim3(256), 0, stream>>>(ctx, cmask, W, mu, pr, (float*)d_out);
}

// Round 3
// 179.262 us; speedup vs baseline: 1.2054x; 1.2054x over previous
//
#include <hip/hip_runtime.h>
#include <math.h>

#define C_ 512
#define D_ 256
#define KS_ 4
#define TOPK_ 10
#define NEG 1e20f

// chunk permutation: XOR bit0 with bit3 (involution). A wave's 64 b128 reads
// (chunks 2l, 2l+1) then cover all 32 banks exactly 8x -> conflict-free.
__device__ __forceinline__ int csw2(int g) { return g ^ ((g >> 3) & 1); }

#define BSTR 516   // b_s row stride (floats): ==4 mod 32 -> transposed scalar writes 2-way max; *4B % 16 == 0
#define ASTR 36    // a_s row stride (floats): multiple of 4 for b128-aligned broadcast reads

extern "C" __global__ __launch_bounds__(256, 3)
void graph_learner(const float* __restrict__ ctx,
                   const int* __restrict__ cmask,
                   const float* __restrict__ W,
                   const float* __restrict__ mu_g,
                   const float* __restrict__ pr_g,
                   float* __restrict__ out)
{
    __shared__ __align__(16) float wbar_s[D_];
    __shared__ __align__(16) float a_s[16 * ASTR];   // A k-slice transposed: a_s[kk*ASTR + r], r=0..31
    __shared__ __align__(16) float b_s[16 * BSTR];   // B k-slice transposed+swizzled
    __shared__ unsigned int vmask_s[16];

    const int tid  = threadIdx.x;
    const int lane = tid & 63;
    const int wv   = tid >> 6;
    const int w8   = wv * 8;

    // XCD swizzle: the 16 row-blocks sharing one ctx[b,t] panel land on one XCD's L2
    const int blk = blockIdx.x;
    const int bt  = (blk & 7) * 4 + ((blk >> 3) & 3);   // 0..31
    const int c0  = (blk >> 5) * 32;                    // row tile 0..480
    const int b   = bt >> 3;

    const float* ctx_bt = ctx + (size_t)bt * (C_ * D_);
    const int*   mask_b = cmask + b * C_;

    // wbar = mean_p relu(W[p,:])
    {
        float w0 = W[tid], w1 = W[D_ + tid], w2 = W[2 * D_ + tid], w3 = W[3 * D_ + tid];
        wbar_s[tid] = 0.25f * (fmaxf(w0, 0.f) + fmaxf(w1, 0.f) + fmaxf(w2, 0.f) + fmaxf(w3, 0.f));
    }
    if (tid < 16) {
        unsigned int m = 0;
        for (int i = 0; i < 32; ++i)
            m |= (mask_b[tid * 32 + i] > 0 ? 1u : 0u) << i;
        vmask_s[tid] = m;
    }
    // zero this block's own output region (4 ks x 32 rows x 512); barriers below
    // order these stores before the epilogue scatter to the same region.
    {
        const float4 z = make_float4(0.f, 0.f, 0.f, 0.f);
        #pragma unroll
        for (int ks = 0; ks < KS_; ++ks) {
            float* ob = out + ((size_t)(bt * KS_ + ks) * C_ + c0) * C_;
            #pragma unroll
            for (int i = 0; i < 16; ++i)
                *(float4*)(ob + (size_t)(tid + i * 256) * 4) = z;
        }
    }

    // ---- hoisted staging geometry ----
    // B: thread loads float4 = ctx[r_i][kt*16 + 4*bq ..], r_i = brow + i*64
    const int brow = tid >> 2;
    const int bq   = tid & 3;
    const float* bsrc = ctx_bt + (size_t)brow * D_ + bq * 4;
    // dst: row (4*bq + j), col 4*csw2(brow>>2) + (brow&3); csw2(g+16i) = csw2(g)+16i
    const int bwbase = (4 * bq) * BSTR + 4 * csw2(brow >> 2) + (brow & 3);
    // A: threads 0..127 load float4 = ctx[c0 + ar][kt*16 + 4*aq ..], ar = 0..31
    const int ar_ = tid >> 2;        // valid when tid<128
    const int aq  = tid & 3;
    const float* asrc = ctx_bt + (size_t)(c0 + ar_) * D_ + aq * 4;
    const int awbase = (4 * aq) * ASTR + ar_;
    // FMA-loop read addresses (swizzled): cols lane*8..lane*8+7
    const int bc0 = 4 * csw2(2 * lane);
    const int bc1 = 4 * csw2(2 * lane + 1);

    float4 bregs[8];
    float4 areg;
    {   // prologue load, k-tile 0
        #pragma unroll
        for (int i = 0; i < 8; ++i)
            bregs[i] = *(const float4*)(bsrc + (size_t)i * 64 * D_);
        if (tid < 128) areg = *(const float4*)(asrc);
    }

    float acc[8][8];
    #pragma unroll
    for (int j = 0; j < 8; ++j)
        #pragma unroll
        for (int i = 0; i < 8; ++i) acc[j][i] = 0.f;

    for (int kt = 0; kt < 16; ++kt) {
        __syncthreads();                 // previous slice fully consumed (and wbar/vmask ready at kt=0)
        #pragma unroll
        for (int i = 0; i < 8; ++i) {
            b_s[bwbase + 0 * BSTR + i * 64] = bregs[i].x;
            b_s[bwbase + 1 * BSTR + i * 64] = bregs[i].y;
            b_s[bwbase + 2 * BSTR + i * 64] = bregs[i].z;
            b_s[bwbase + 3 * BSTR + i * 64] = bregs[i].w;
        }
        if (tid < 128) {
            float4 wb = *(const float4*)(wbar_s + kt * 16 + aq * 4);
            a_s[awbase + 0 * ASTR] = areg.x * wb.x;
            a_s[awbase + 1 * ASTR] = areg.y * wb.y;
            a_s[awbase + 2 * ASTR] = areg.z * wb.z;
            a_s[awbase + 3 * ASTR] = areg.w * wb.w;
        }
        __syncthreads();
        if (kt < 15) {                   // T14: next-slice loads hide under the FMA block
            #pragma unroll
            for (int i = 0; i < 8; ++i)
                bregs[i] = *(const float4*)(bsrc + (size_t)i * 64 * D_ + (kt + 1) * 16);
            if (tid < 128) areg = *(const float4*)(asrc + (kt + 1) * 16);
        }
        #pragma unroll
        for (int kk = 0; kk < 16; ++kk) {
            float4 av0 = *(const float4*)(a_s + kk * ASTR + w8);       // wave-uniform broadcast
            float4 av1 = *(const float4*)(a_s + kk * ASTR + w8 + 4);
            float4 bv0 = *(const float4*)(b_s + kk * BSTR + bc0);
            float4 bv1 = *(const float4*)(b_s + kk * BSTR + bc1);
            float ar8[8] = {av0.x, av0.y, av0.z, av0.w, av1.x, av1.y, av1.z, av1.w};
            float br8[8] = {bv0.x, bv0.y, bv0.z, bv0.w, bv1.x, bv1.y, bv1.z, bv1.w};
            #pragma unroll
            for (int j = 0; j < 8; ++j)
                #pragma unroll
                for (int i = 0; i < 8; ++i)
                    acc[j][i] += ar8[j] * br8[i];   // sequential over d: matches ref accumulation
        }
    }

    // ---- epilogue: mask, top-10, softmax, spatial, scatter ----
    const unsigned int em8 = (vmask_s[lane >> 2] >> ((lane & 3) * 8)) & 0xffu;
    const float mu0 = mu_g[0], mu1 = mu_g[1], mu2 = mu_g[2], mu3 = mu_g[3];
    const float pr0 = pr_g[0], pr1 = pr_g[1], pr2 = pr_g[2], pr3 = pr_g[3];

    #pragma unroll
    for (int jr = 0; jr < 8; ++jr) {
        const int c  = c0 + w8 + jr;
        const int vr = mask_b[c];
        float row[8];
        #pragma unroll
        for (int i = 0; i < 8; ++i) {
            bool ok = (vr > 0) && ((em8 >> i) & 1u);
            row[i] = ok ? acc[jr][i] : -NEG;
        }
        float tv[TOPK_];
        int   te[TOPK_];
        unsigned int taken = 0;
        #pragma unroll
        for (int j = 0; j < TOPK_; ++j) {
            float lv = -3.3e38f;
            int   li = 0;
            #pragma unroll
            for (int i = 0; i < 8; ++i) {
                bool better = (!((taken >> i) & 1u)) && (row[i] > lv);
                lv = better ? row[i] : lv;
                li = better ? i : li;
            }
            int le = lane * 8 + li;
            #pragma unroll
            for (int off = 1; off < 64; off <<= 1) {
                float ov = __shfl_xor(lv, off);
                int   oe = __shfl_xor(le, off);
                bool take = (ov > lv) || (ov == lv && oe < le);
                lv = take ? ov : lv;
                le = take ? oe : le;
            }
            tv[j] = lv;
            te[j] = le;
            if ((le >> 3) == lane) taken |= 1u << (le & 7);
        }
        const float mx = tv[0];
        float ssum = 0.f;
        #pragma unroll
        for (int j = 0; j < TOPK_; ++j) ssum += expf(tv[j] - mx);

        if (lane < 40) {
            const int ksq = lane / 10;
            const int myj = lane - ksq * 10;
            const float mu = (ksq == 0) ? mu0 : (ksq == 1) ? mu1 : (ksq == 2) ? mu2 : mu3;
            const float pr = (ksq == 0) ? pr0 : (ksq == 1) ? pr1 : (ksq == 2) ? pr2 : pr3;
            float sps = 0.f, spj = 0.f, tvj = 0.f;
            int ej = 0;
            #pragma unroll
            for (int j = 0; j < TOPK_; ++j) {
                float d = fabsf((float)(te[j] - c));
                d = fminf(d, 160.f) * (1.0f / 160.0f);
                float x  = d - mu;
                float sp = expf(-0.5f * x * x * pr * pr);
                sps += sp;
                if (j == myj) { spj = sp; tvj = tv[j]; ej = te[j]; }
            }
            float val = (expf(tvj - mx) / ssum) * (spj / sps);
            out[((size_t)(bt * KS_ + ksq) * C_ + c) * C_ + ej] = val;
        }
    }
}

extern "C" void kernel_launch(void* const* d_in, const int* in_sizes, int n_in,
                              void* d_out, int out_size, void* d_ws, size_t ws_size,
                              hipStream_t stream) {
    (void)in_sizes; (void)n_in; (void)d_ws; (void)ws_size; (void)out_size;
    const float* ctx   = (const float*)d_in[0];
    const int*   cmask = (const int*)d_in[1];
    const float* W     = (const float*)d_in[2];
    const float* mu    = (const float*)d_in[3];
    const float* pr    = (const float*)d_in[4];
    graph_learner<<<dim3(512), dim3(256), 0, stream>>>(ctx, cmask, W, mu, pr, (float*)d_out);
}

// Round 4
// 131.862 us; speedup vs baseline: 1.6387x; 1.3595x over previous
//
#include <hip/hip_runtime.h>
#include <math.h>

#define C_ 512
#define D_ 256
#define KS_ 4
#define TOPK_ 10
#define NEG 1e20f

// chunk permutation: XOR bit0 with bit3 (involution). A wave's 64 b128 reads
// (chunks 2l, 2l+1) cover all 32 banks with only 2-way aliasing (free, m136).
__device__ __forceinline__ int csw2(int g) { return g ^ ((g >> 3) & 1); }

#define BSTR 516   // b_s row stride (floats): ==4 mod 32 -> transposed scalar writes conflict-free; *4B % 16 == 0
#define ASTR 36    // a_s row stride (floats): multiple of 4 for b128-aligned broadcast reads

// NOTE: on this toolchain __launch_bounds__(256,w) empirically caps VGPRs at 256/w
// (R1/R2/R3 measured 128/64/84). w=2 -> cap 128 = the 4-waves/SIMD HW boundary.
extern "C" __global__ __launch_bounds__(256, 2)
void graph_learner(const float* __restrict__ ctx,
                   const int* __restrict__ cmask,
                   const float* __restrict__ W,
                   const float* __restrict__ mu_g,
                   const float* __restrict__ pr_g,
                   float* __restrict__ out)
{
    __shared__ __align__(16) float wbar_s[D_];
    __shared__ __align__(16) float a_s[16 * ASTR];   // A k-slice transposed: a_s[kk*ASTR + r], r=0..31
    __shared__ __align__(16) float b_s[16 * BSTR];   // B k-slice transposed+swizzled
    __shared__ unsigned int vmask_s[16];

    const int tid  = threadIdx.x;
    const int lane = tid & 63;
    const int wv   = tid >> 6;
    const int w8   = wv * 8;

    // XCD swizzle: the 16 row-blocks sharing one ctx[b,t] panel land on one XCD's L2
    const int blk = blockIdx.x;
    const int bt  = (blk & 7) * 4 + ((blk >> 3) & 3);   // 0..31
    const int c0  = (blk >> 5) * 32;                    // row tile 0..480
    const int b   = bt >> 3;

    const float* ctx_bt = ctx + (size_t)bt * (C_ * D_);
    const int*   mask_b = cmask + b * C_;

    // wbar = mean_p relu(W[p,:])
    {
        float w0 = W[tid], w1 = W[D_ + tid], w2 = W[2 * D_ + tid], w3 = W[3 * D_ + tid];
        wbar_s[tid] = 0.25f * (fmaxf(w0, 0.f) + fmaxf(w1, 0.f) + fmaxf(w2, 0.f) + fmaxf(w3, 0.f));
    }
    if (tid < 16) {
        unsigned int m = 0;
        for (int i = 0; i < 32; ++i)
            m |= (mask_b[tid * 32 + i] > 0 ? 1u : 0u) << i;
        vmask_s[tid] = m;
    }
    // zero this block's own output region (4 ks x 32 rows x 512); the k-loop
    // barriers (with their vmcnt drains) order these before the epilogue scatter.
    {
        const float4 z = make_float4(0.f, 0.f, 0.f, 0.f);
        #pragma unroll
        for (int ks = 0; ks < KS_; ++ks) {
            float* ob = out + ((size_t)(bt * KS_ + ks) * C_ + c0) * C_;
            #pragma unroll
            for (int i = 0; i < 16; ++i)
                *(float4*)(ob + (size_t)(tid + i * 256) * 4) = z;
        }
    }

    // ---- hoisted staging geometry ----
    // B: thread loads float4 = ctx[r_i][kt*16 + 4*bq ..], r_i = brow + i*64
    const int brow = tid >> 2;
    const int bq   = tid & 3;
    const float* bsrc = ctx_bt + (size_t)brow * D_ + bq * 4;
    // dst: row (4*bq + j), col 4*csw2(brow>>2) + (brow&3); csw2(g+16i) = csw2(g)+16i
    const int bwbase = (4 * bq) * BSTR + 4 * csw2(brow >> 2) + (brow & 3);
    // A: threads 0..127 load float4 = ctx[c0 + ar][kt*16 + 4*aq ..], ar = 0..31
    const int ar_ = tid >> 2;        // valid when tid<128
    const int aq  = tid & 3;
    const float* asrc = ctx_bt + (size_t)(c0 + ar_) * D_ + aq * 4;
    const int awbase = (4 * aq) * ASTR + ar_;
    // FMA-loop read addresses (swizzled): cols lane*8..lane*8+7
    const int bc0 = 4 * csw2(2 * lane);
    const int bc1 = 4 * csw2(2 * lane + 1);

    float acc[8][8];
    #pragma unroll
    for (int j = 0; j < 8; ++j)
        #pragma unroll
        for (int i = 0; i < 8; ++i) acc[j][i] = 0.f;

    for (int kt = 0; kt < 16; ++kt) {
        __syncthreads();                 // previous slice fully consumed (and wbar/vmask ready at kt=0)
        // register-frugal staging: load -> immediate LDS write (R1 shape, fits 128 VGPR)
        #pragma unroll
        for (int i = 0; i < 8; ++i) {
            float4 v = *(const float4*)(bsrc + (size_t)i * 64 * D_ + kt * 16);
            b_s[bwbase + 0 * BSTR + i * 64] = v.x;
            b_s[bwbase + 1 * BSTR + i * 64] = v.y;
            b_s[bwbase + 2 * BSTR + i * 64] = v.z;
            b_s[bwbase + 3 * BSTR + i * 64] = v.w;
        }
        if (tid < 128) {
            float4 v  = *(const float4*)(asrc + kt * 16);
            float4 wb = *(const float4*)(wbar_s + kt * 16 + aq * 4);
            a_s[awbase + 0 * ASTR] = v.x * wb.x;
            a_s[awbase + 1 * ASTR] = v.y * wb.y;
            a_s[awbase + 2 * ASTR] = v.z * wb.z;
            a_s[awbase + 3 * ASTR] = v.w * wb.w;
        }
        __syncthreads();
        #pragma unroll
        for (int kk = 0; kk < 16; ++kk) {
            float4 av0 = *(const float4*)(a_s + kk * ASTR + w8);       // wave-uniform broadcast
            float4 av1 = *(const float4*)(a_s + kk * ASTR + w8 + 4);
            float4 bv0 = *(const float4*)(b_s + kk * BSTR + bc0);
            float4 bv1 = *(const float4*)(b_s + kk * BSTR + bc1);
            float ar8[8] = {av0.x, av0.y, av0.z, av0.w, av1.x, av1.y, av1.z, av1.w};
            float br8[8] = {bv0.x, bv0.y, bv0.z, bv0.w, bv1.x, bv1.y, bv1.z, bv1.w};
            #pragma unroll
            for (int j = 0; j < 8; ++j)
                #pragma unroll
                for (int i = 0; i < 8; ++i)
                    acc[j][i] += ar8[j] * br8[i];   // sequential over d: matches ref accumulation
        }
    }

    // ---- epilogue: mask, top-10, softmax, spatial, scatter ----
    const unsigned int em8 = (vmask_s[lane >> 2] >> ((lane & 3) * 8)) & 0xffu;
    const float mu0 = mu_g[0], mu1 = mu_g[1], mu2 = mu_g[2], mu3 = mu_g[3];
    const float pr0 = pr_g[0], pr1 = pr_g[1], pr2 = pr_g[2], pr3 = pr_g[3];

    #pragma unroll
    for (int jr = 0; jr < 8; ++jr) {
        const int c  = c0 + w8 + jr;
        const int vr = mask_b[c];
        float row[8];
        #pragma unroll
        for (int i = 0; i < 8; ++i) {
            bool ok = (vr > 0) && ((em8 >> i) & 1u);
            row[i] = ok ? acc[jr][i] : -NEG;
        }
        float tv[TOPK_];
        int   te[TOPK_];
        unsigned int taken = 0;
        #pragma unroll
        for (int j = 0; j < TOPK_; ++j) {
            float lv = -3.3e38f;
            int   li = 0;
            #pragma unroll
            for (int i = 0; i < 8; ++i) {
                bool better = (!((taken >> i) & 1u)) && (row[i] > lv);
                lv = better ? row[i] : lv;
                li = better ? i : li;
            }
            int le = lane * 8 + li;
            #pragma unroll
            for (int off = 1; off < 64; off <<= 1) {
                float ov = __shfl_xor(lv, off);
                int   oe = __shfl_xor(le, off);
                bool take = (ov > lv) || (ov == lv && oe < le);
                lv = take ? ov : lv;
                le = take ? oe : le;
            }
            tv[j] = lv;
            te[j] = le;
            if ((le >> 3) == lane) taken |= 1u << (le & 7);
        }
        const float mx = tv[0];
        float ssum = 0.f;
        #pragma unroll
        for (int j = 0; j < TOPK_; ++j) ssum += expf(tv[j] - mx);

        if (lane < 40) {
            const int ksq = lane / 10;
            const int myj = lane - ksq * 10;
            const float mu = (ksq == 0) ? mu0 : (ksq == 1) ? mu1 : (ksq == 2) ? mu2 : mu3;
            const float pr = (ksq == 0) ? pr0 : (ksq == 1) ? pr1 : (ksq == 2) ? pr2 : pr3;
            float sps = 0.f, spj = 0.f, tvj = 0.f;
            int ej = 0;
            #pragma unroll
            for (int j = 0; j < TOPK_; ++j) {
                float d = fabsf((float)(te[j] - c));
                d = fminf(d, 160.f) * (1.0f / 160.0f);
                float x  = d - mu;
                float sp = expf(-0.5f * x * x * pr * pr);
                sps += sp;
                if (j == myj) { spj = sp; tvj = tv[j]; ej = te[j]; }
            }
            float val = (expf(tvj - mx) / ssum) * (spj / sps);
            out[((size_t)(bt * KS_ + ksq) * C_ + c) * C_ + ej] = val;
        }
    }
}

extern "C" void kernel_launch(void* const* d_in, const int* in_sizes, int n_in,
                              void* d_out, int out_size, void* d_ws, size_t ws_size,
                              hipStream_t stream) {
    (void)in_sizes; (void)n_in; (void)d_ws; (void)ws_size; (void)out_size;
    const float* ctx   = (const float*)d_in[0];
    const int*   cmask = (const int*)d_in[1];
    const float* W     = (const float*)d_in[2];
    const float* mu    = (const float*)d_in[3];
    const float* pr    = (const float*)d_in[4];
    graph_learner<<<dim3(512), dim3(256), 0, stream>>>(ctx, cmask, W, mu, pr, (float*)d_out);
}